// Round 6
// baseline (278.982 us; speedup 1.0000x reference)
//
#include <hip/hip_runtime.h>

// z: [64, 256, 32, 32] f32 ; codebook: [512, 256] f32
// d_out is FLOAT32: [z_q_st (16777216) | indices (65536) | loss (1)]
#define C_DIM   256
#define K_CODES 512
#define N_POS   65536
#define OUT0_ELEMS 16777216
#define OUT1_ELEMS 65536

// ---------------------------------------------------------------------------
// transpose codebook -> cbT[c][k]
// ---------------------------------------------------------------------------
__global__ __launch_bounds__(256) void vq_transpose_kernel(const float* __restrict__ cb,
                                                           float* __restrict__ cbT)
{
    const int k = blockIdx.x;      // 0..511
    const int c = threadIdx.x;     // 0..255
    cbT[c * K_CODES + k] = cb[k * C_DIM + c];
}

// ---------------------------------------------------------------------------
// cc[k] = sum_c cb[k][c]^2, numpy pairwise order (two 128-blocks, 8 accs each)
// ---------------------------------------------------------------------------
__global__ __launch_bounds__(256) void vq_cc_kernel(const float* __restrict__ cbT,
                                                    float* __restrict__ cc)
{
    const int k = blockIdx.x * 256 + threadIdx.x;   // 0..511
    float s1[8], s2[8];
    #pragma unroll
    for (int j = 0; j < 8; ++j) { s1[j] = 0.f; s2[j] = 0.f; }
    for (int c8 = 0; c8 < 16; ++c8) {
        #pragma unroll
        for (int j = 0; j < 8; ++j) {
            float v = cbT[(c8 * 8 + j) * K_CODES + k];
            s1[j] = __fadd_rn(s1[j], __fmul_rn(v, v));
        }
    }
    for (int c8 = 16; c8 < 32; ++c8) {
        #pragma unroll
        for (int j = 0; j < 8; ++j) {
            float v = cbT[(c8 * 8 + j) * K_CODES + k];
            s2[j] = __fadd_rn(s2[j], __fmul_rn(v, v));
        }
    }
    float b1 = __fadd_rn(__fadd_rn(__fadd_rn(s1[0], s1[1]), __fadd_rn(s1[2], s1[3])),
                         __fadd_rn(__fadd_rn(s1[4], s1[5]), __fadd_rn(s1[6], s1[7])));
    float b2 = __fadd_rn(__fadd_rn(__fadd_rn(s2[0], s2[1]), __fadd_rn(s2[2], s2[3])),
                         __fadd_rn(__fadd_rn(s2[4], s2[5]), __fadd_rn(s2[6], s2[7])));
    cc[k] = __fadd_rn(b1, b2);
}

// ---------------------------------------------------------------------------
// zz[pos] = sum_c z[pos][c]^2, np-pairwise structure (unchanged, passed)
// ---------------------------------------------------------------------------
__global__ __launch_bounds__(256) void vq_zz_kernel(const float* __restrict__ z,
                                                    float* __restrict__ zz)
{
    const int pos = blockIdx.x * 256 + threadIdx.x;      // 0..65535
    const float* zp = z + ((size_t)(pos >> 10) << 18) + (pos & 1023);
    float s1[8], s2[8];
    #pragma unroll
    for (int j = 0; j < 8; ++j) { s1[j] = 0.f; s2[j] = 0.f; }
    for (int c8 = 0; c8 < 16; ++c8) {
        #pragma unroll
        for (int j = 0; j < 8; ++j) {
            float v = zp[(size_t)(c8 * 8 + j) << 10];
            s1[j] = __fadd_rn(s1[j], __fmul_rn(v, v));
        }
    }
    for (int c8 = 16; c8 < 32; ++c8) {
        #pragma unroll
        for (int j = 0; j < 8; ++j) {
            float v = zp[(size_t)(c8 * 8 + j) << 10];
            s2[j] = __fadd_rn(s2[j], __fmul_rn(v, v));
        }
    }
    float b1 = __fadd_rn(__fadd_rn(__fadd_rn(s1[0], s1[1]), __fadd_rn(s1[2], s1[3])),
                         __fadd_rn(__fadd_rn(s1[4], s1[5]), __fadd_rn(s1[6], s1[7])));
    float b2 = __fadd_rn(__fadd_rn(__fadd_rn(s2[0], s2[1]), __fadd_rn(s2[2], s2[3])),
                         __fadd_rn(__fadd_rn(s2[4], s2[5]), __fadd_rn(s2[6], s2[7])));
    zz[pos] = __fadd_rn(b1, b2);
}

// ---------------------------------------------------------------------------
// Main: grid 1024 = chunk(256 positions)(256) x code-group(4).
// Block = 4 waves; wave w owns codes cg*128 + w*32 .. +32.
// Each thread: 4 positions (lane, lane+64, lane+128, lane+192 within chunk)
// x 32 codes -> acc[4][32] in registers. Per c: 4 coalesced z loads + 32
// wave-uniform cbT floats (s_load) + 128 FMAs. Numerics identical to R5:
// ascending-c FMA chain, d = fl(fl(zz-2*dot)+cc), ascending-code tie-break.
// ---------------------------------------------------------------------------
__global__ __launch_bounds__(256, 3) void vq_main_kernel(
    const float* __restrict__ z, const float* __restrict__ cbT,
    const float* __restrict__ ccv, const float* __restrict__ zzbuf,
    float* __restrict__ bd, int* __restrict__ bc)
{
    const int blk   = blockIdx.x;            // 0..1023
    const int cg    = blk & 3;               // code group (128 codes)
    const int chunk = blk >> 2;              // 0..255 (256 positions each)
    const int b     = chunk >> 2;            // image (4 chunks per image)
    const int hw0   = (chunk & 3) << 8;      // 0,256,512,768
    const int tid   = threadIdx.x;
    const int lane  = tid & 63;
    const int w     = tid >> 6;

    const float* zp = z + ((size_t)b << 18) + hw0 + lane;   // + p*64 + (c<<10)
    const int cb0   = __builtin_amdgcn_readfirstlane((cg << 7) + (w << 5));
    const float* cbbase = cbT + cb0;

    float acc[4][32];
    #pragma unroll
    for (int p = 0; p < 4; ++p)
        #pragma unroll
        for (int k = 0; k < 32; ++k) acc[p][k] = 0.f;

    for (int c = 0; c < C_DIM; ++c) {
        const float* zc = zp + ((size_t)c << 10);
        const float zv0 = zc[0];
        const float zv1 = zc[64];
        const float zv2 = zc[128];
        const float zv3 = zc[192];
        const float* cbrow = cbbase + (c << 9);
        #pragma unroll
        for (int k = 0; k < 32; ++k) {
            const float cv = cbrow[k];
            acc[0][k] = __builtin_fmaf(zv0, cv, acc[0][k]);
            acc[1][k] = __builtin_fmaf(zv1, cv, acc[1][k]);
            acc[2][k] = __builtin_fmaf(zv2, cv, acc[2][k]);
            acc[3][k] = __builtin_fmaf(zv3, cv, acc[3][k]);
        }
    }

    __shared__ float sdm[4][4][64];
    __shared__ int   sco[4][4][64];

    const float* ccp = ccv + cb0;
    const int posb = (b << 10) + hw0 + lane;
    #pragma unroll
    for (int p = 0; p < 4; ++p) {
        const float zzv = zzbuf[posb + p * 64];
        float bestd = 3.4e38f;
        int   bestc = cb0;
        #pragma unroll
        for (int k = 0; k < 32; ++k) {
            float d = __fadd_rn(__fsub_rn(zzv, __fmul_rn(2.0f, acc[p][k])), ccp[k]);
            if (d < bestd) { bestd = d; bestc = cb0 + k; }   // ascending code
        }
        sdm[w][p][lane] = bestd;
        sco[w][p][lane] = bestc;
    }
    __syncthreads();

    if (w == 0) {
        #pragma unroll
        for (int p = 0; p < 4; ++p) {
            float bdv = sdm[0][p][lane];
            int   bcv = sco[0][p][lane];
            #pragma unroll
            for (int ww = 1; ww < 4; ++ww) {      // ascending wave = ascending code
                float d2 = sdm[ww][p][lane];
                int   c2 = sco[ww][p][lane];
                if (d2 < bdv || (d2 == bdv && c2 < bcv)) { bdv = d2; bcv = c2; }
            }
            bd[(cg << 16) + posb + p * 64] = bdv;
            bc[(cg << 16) + posb + p * 64] = bcv;
        }
    }
}

// ---------------------------------------------------------------------------
// Combine: per position, min over 4 code-group partials (tie -> smaller code).
// ---------------------------------------------------------------------------
__global__ __launch_bounds__(256) void vq_combine_kernel(
    const float* __restrict__ bd, const int* __restrict__ bc,
    int* __restrict__ idx, float* __restrict__ out1, float* __restrict__ partials)
{
    const int t   = threadIdx.x;
    const int pos = blockIdx.x * 256 + t;
    float bdv = bd[pos];
    int   bcv = bc[pos];
    #pragma unroll
    for (int g = 1; g < 4; ++g) {
        float d2 = bd[(g << 16) + pos];
        int   c2 = bc[(g << 16) + pos];
        if (d2 < bdv || (d2 == bdv && c2 < bcv)) { bdv = d2; bcv = c2; }
    }
    idx[pos]  = bcv;
    out1[pos] = (float)bcv;

    __shared__ float s[256];
    s[t] = bdv;
    __syncthreads();
    for (int off = 128; off > 0; off >>= 1) {
        if (t < off) s[t] += s[t + off];
        __syncthreads();
    }
    if (t == 0) partials[blockIdx.x] = s[0];
}

// ---------------------------------------------------------------------------
// Gather: out0[b, c, hw] = cb[code][c]  (f32)
// ---------------------------------------------------------------------------
__global__ __launch_bounds__(256) void vq_gather_kernel(
    const float* __restrict__ cb, const int* __restrict__ idx,
    float* __restrict__ out0)
{
    const int blk = blockIdx.x;          // 1024
    const int b   = blk >> 4;
    const int hw0 = (blk & 15) << 6;
    const int lane = threadIdx.x & 63;
    const int w    = threadIdx.x >> 6;

    __shared__ int sidx[64];
    if (threadIdx.x < 64) sidx[threadIdx.x] = idx[(blk << 6) + threadIdx.x];
    __syncthreads();

    const int code = sidx[lane];
    const float4* crow4 = reinterpret_cast<const float4*>(cb + ((size_t)code << 8) + (w << 6));
    float* ob = out0 + ((size_t)b << 18) + ((size_t)(w * 64) << 10) + hw0 + lane;
    #pragma unroll 4
    for (int j4 = 0; j4 < 16; ++j4) {
        float4 v = crow4[j4];
        ob[(size_t)(j4 * 4 + 0) << 10] = v.x;
        ob[(size_t)(j4 * 4 + 1) << 10] = v.y;
        ob[(size_t)(j4 * 4 + 2) << 10] = v.z;
        ob[(size_t)(j4 * 4 + 3) << 10] = v.w;
    }
}

// ---------------------------------------------------------------------------
// Finalize: loss = 1.25 * sum(partials[0..255]) / 2^24
// ---------------------------------------------------------------------------
__global__ __launch_bounds__(256) void vq_finalize_kernel(
    const float* __restrict__ partials, float* __restrict__ out2)
{
    __shared__ float s[256];
    const int t = threadIdx.x;
    s[t] = partials[t];
    __syncthreads();
    for (int off = 128; off > 0; off >>= 1) {
        if (t < off) s[t] += s[t + off];
        __syncthreads();
    }
    if (t == 0)
        out2[0] = 1.25f * (s[0] * (1.0f / 16777216.0f));
}

// ---------------------------------------------------------------------------
extern "C" void kernel_launch(void* const* d_in, const int* in_sizes, int n_in,
                              void* d_out, int out_size, void* d_ws, size_t ws_size,
                              hipStream_t stream)
{
    const float* z  = (const float*)d_in[0];
    const float* cb = (const float*)d_in[1];

    float* out0 = (float*)d_out;                  // z_q_st  (16777216 f32)
    float* out1 = out0 + OUT0_ELEMS;              // indices (65536 f32)
    float* out2 = out0 + OUT0_ELEMS + OUT1_ELEMS; // loss    (1 f32)

    // scratch carved from the out0 region (free until the gather runs):
    float* bd = out0;                        // 4*65536 f32 (1 MB)
    int*   bc = (int*)(out0 + 4 * N_POS);    // 4*65536 i32 (1 MB)
    float* zz = out0 + 8 * N_POS;            // 65536 f32  (256 KB)

    // ws: partials | cc | cbT | idx  (~790 KB)
    float* wsf      = (float*)d_ws;
    float* partials = wsf;                   // 256 f32
    float* ccv      = wsf + 256;             // 512 f32
    float* cbT      = wsf + 1024;            // 131072 f32
    int*   idx      = (int*)(wsf + 1024 + C_DIM * K_CODES);  // 65536 i32

    hipLaunchKernelGGL(vq_transpose_kernel, dim3(512),  dim3(256), 0, stream, cb, cbT);
    hipLaunchKernelGGL(vq_cc_kernel,        dim3(2),    dim3(256), 0, stream, cbT, ccv);
    hipLaunchKernelGGL(vq_zz_kernel,        dim3(256),  dim3(256), 0, stream, z, zz);
    hipLaunchKernelGGL(vq_main_kernel,      dim3(1024), dim3(256), 0, stream,
                       z, cbT, ccv, zz, bd, bc);
    hipLaunchKernelGGL(vq_combine_kernel,   dim3(256),  dim3(256), 0, stream,
                       bd, bc, idx, out1, partials);
    hipLaunchKernelGGL(vq_gather_kernel,    dim3(1024), dim3(256), 0, stream, cb, idx, out0);
    hipLaunchKernelGGL(vq_finalize_kernel,  dim3(1),    dim3(256), 0, stream, partials, out2);
}

// Round 7
// 224.700 us; speedup vs baseline: 1.2416x; 1.2416x over previous
//
#include <hip/hip_runtime.h>

// z: [64, 256, 32, 32] f32 ; codebook: [512, 256] f32
// d_out is FLOAT32: [z_q_st (16777216) | indices (65536) | loss (1)]
#define C_DIM   256
#define K_CODES 512
#define N_POS   65536
#define OUT0_ELEMS 16777216
#define OUT1_ELEMS 65536

// ---------------------------------------------------------------------------
// transpose codebook -> cbT[c][k]
// ---------------------------------------------------------------------------
__global__ __launch_bounds__(256) void vq_transpose_kernel(const float* __restrict__ cb,
                                                           float* __restrict__ cbT)
{
    const int k = blockIdx.x;      // 0..511
    const int c = threadIdx.x;     // 0..255
    cbT[c * K_CODES + k] = cb[k * C_DIM + c];
}

// ---------------------------------------------------------------------------
// cc[k] = sum_c cb[k][c]^2, numpy pairwise order (two 128-blocks, 8 accs each)
// ---------------------------------------------------------------------------
__global__ __launch_bounds__(256) void vq_cc_kernel(const float* __restrict__ cbT,
                                                    float* __restrict__ cc)
{
    const int k = blockIdx.x * 256 + threadIdx.x;   // 0..511
    float s1[8], s2[8];
    #pragma unroll
    for (int j = 0; j < 8; ++j) { s1[j] = 0.f; s2[j] = 0.f; }
    for (int c8 = 0; c8 < 16; ++c8) {
        #pragma unroll
        for (int j = 0; j < 8; ++j) {
            float v = cbT[(c8 * 8 + j) * K_CODES + k];
            s1[j] = __fadd_rn(s1[j], __fmul_rn(v, v));
        }
    }
    for (int c8 = 16; c8 < 32; ++c8) {
        #pragma unroll
        for (int j = 0; j < 8; ++j) {
            float v = cbT[(c8 * 8 + j) * K_CODES + k];
            s2[j] = __fadd_rn(s2[j], __fmul_rn(v, v));
        }
    }
    float b1 = __fadd_rn(__fadd_rn(__fadd_rn(s1[0], s1[1]), __fadd_rn(s1[2], s1[3])),
                         __fadd_rn(__fadd_rn(s1[4], s1[5]), __fadd_rn(s1[6], s1[7])));
    float b2 = __fadd_rn(__fadd_rn(__fadd_rn(s2[0], s2[1]), __fadd_rn(s2[2], s2[3])),
                         __fadd_rn(__fadd_rn(s2[4], s2[5]), __fadd_rn(s2[6], s2[7])));
    cc[k] = __fadd_rn(b1, b2);
}

// ---------------------------------------------------------------------------
// zz[pos] = sum_c z[pos][c]^2, np-pairwise structure (unchanged, passed)
// ---------------------------------------------------------------------------
__global__ __launch_bounds__(256) void vq_zz_kernel(const float* __restrict__ z,
                                                    float* __restrict__ zz)
{
    const int pos = blockIdx.x * 256 + threadIdx.x;      // 0..65535
    const float* zp = z + ((size_t)(pos >> 10) << 18) + (pos & 1023);
    float s1[8], s2[8];
    #pragma unroll
    for (int j = 0; j < 8; ++j) { s1[j] = 0.f; s2[j] = 0.f; }
    for (int c8 = 0; c8 < 16; ++c8) {
        #pragma unroll
        for (int j = 0; j < 8; ++j) {
            float v = zp[(size_t)(c8 * 8 + j) << 10];
            s1[j] = __fadd_rn(s1[j], __fmul_rn(v, v));
        }
    }
    for (int c8 = 16; c8 < 32; ++c8) {
        #pragma unroll
        for (int j = 0; j < 8; ++j) {
            float v = zp[(size_t)(c8 * 8 + j) << 10];
            s2[j] = __fadd_rn(s2[j], __fmul_rn(v, v));
        }
    }
    float b1 = __fadd_rn(__fadd_rn(__fadd_rn(s1[0], s1[1]), __fadd_rn(s1[2], s1[3])),
                         __fadd_rn(__fadd_rn(s1[4], s1[5]), __fadd_rn(s1[6], s1[7])));
    float b2 = __fadd_rn(__fadd_rn(__fadd_rn(s2[0], s2[1]), __fadd_rn(s2[2], s2[3])),
                         __fadd_rn(__fadd_rn(s2[4], s2[5]), __fadd_rn(s2[6], s2[7])));
    zz[pos] = __fadd_rn(b1, b2);
}

// ---------------------------------------------------------------------------
// Main: grid 2048 = chunk(128 positions)(512) x code-group(4).
// Block = 4 waves; wave w owns codes cg*128 + w*32 .. +32.
// Each thread: 2 positions (lane, lane+64 within chunk) x 32 codes ->
// acc[2][32] (64 VGPR accs, no launch-bounds cap -> no spills).
// Per c: 2 coalesced z loads + 32 wave-uniform cbT floats (s_load) + 64 FMAs.
// Numerics identical to R5 (passed): ascending-c FMA chain,
// d = fl(fl(zz-2*dot)+cc), ascending-code tie-break.
// ---------------------------------------------------------------------------
__global__ __launch_bounds__(256) void vq_main_kernel(
    const float* __restrict__ z, const float* __restrict__ cbT,
    const float* __restrict__ ccv, const float* __restrict__ zzbuf,
    float* __restrict__ bd, int* __restrict__ bc)
{
    const int blk   = blockIdx.x;            // 0..2047
    const int cg    = blk & 3;               // code group (128 codes)
    const int chunk = blk >> 2;              // 0..511 (128 positions each)
    const int b     = chunk >> 3;            // image (8 chunks per image)
    const int hw0   = (chunk & 7) << 7;      // 0,128,...,896
    const int tid   = threadIdx.x;
    const int lane  = tid & 63;
    const int w     = tid >> 6;

    const float* zp = z + ((size_t)b << 18) + hw0 + lane;   // + p*64 + (c<<10)
    const int cb0   = __builtin_amdgcn_readfirstlane((cg << 7) + (w << 5));
    const float* cbbase = cbT + cb0;

    float acc[2][32];
    #pragma unroll
    for (int p = 0; p < 2; ++p)
        #pragma unroll
        for (int k = 0; k < 32; ++k) acc[p][k] = 0.f;

    for (int c = 0; c < C_DIM; ++c) {
        const float* zc = zp + ((size_t)c << 10);
        const float zv0 = zc[0];
        const float zv1 = zc[64];
        const float* cbrow = cbbase + (c << 9);
        #pragma unroll
        for (int k = 0; k < 32; ++k) {
            const float cv = cbrow[k];
            acc[0][k] = __builtin_fmaf(zv0, cv, acc[0][k]);
            acc[1][k] = __builtin_fmaf(zv1, cv, acc[1][k]);
        }
    }

    __shared__ float sdm[4][2][64];
    __shared__ int   sco[4][2][64];

    const float* ccp = ccv + cb0;
    const int posb = (b << 10) + hw0 + lane;
    #pragma unroll
    for (int p = 0; p < 2; ++p) {
        const float zzv = zzbuf[posb + p * 64];
        float bestd = 3.4e38f;
        int   bestc = cb0;
        #pragma unroll
        for (int k = 0; k < 32; ++k) {
            float d = __fadd_rn(__fsub_rn(zzv, __fmul_rn(2.0f, acc[p][k])), ccp[k]);
            if (d < bestd) { bestd = d; bestc = cb0 + k; }   // ascending code
        }
        sdm[w][p][lane] = bestd;
        sco[w][p][lane] = bestc;
    }
    __syncthreads();

    if (w == 0) {
        #pragma unroll
        for (int p = 0; p < 2; ++p) {
            float bdv = sdm[0][p][lane];
            int   bcv = sco[0][p][lane];
            #pragma unroll
            for (int ww = 1; ww < 4; ++ww) {      // ascending wave = ascending code
                float d2 = sdm[ww][p][lane];
                int   c2 = sco[ww][p][lane];
                if (d2 < bdv || (d2 == bdv && c2 < bcv)) { bdv = d2; bcv = c2; }
            }
            bd[(cg << 16) + posb + p * 64] = bdv;
            bc[(cg << 16) + posb + p * 64] = bcv;
        }
    }
}

// ---------------------------------------------------------------------------
// Combine: per position, min over 4 code-group partials (tie -> smaller code).
// ---------------------------------------------------------------------------
__global__ __launch_bounds__(256) void vq_combine_kernel(
    const float* __restrict__ bd, const int* __restrict__ bc,
    int* __restrict__ idx, float* __restrict__ out1, float* __restrict__ partials)
{
    const int t   = threadIdx.x;
    const int pos = blockIdx.x * 256 + t;
    float bdv = bd[pos];
    int   bcv = bc[pos];
    #pragma unroll
    for (int g = 1; g < 4; ++g) {
        float d2 = bd[(g << 16) + pos];
        int   c2 = bc[(g << 16) + pos];
        if (d2 < bdv || (d2 == bdv && c2 < bcv)) { bdv = d2; bcv = c2; }
    }
    idx[pos]  = bcv;
    out1[pos] = (float)bcv;

    __shared__ float s[256];
    s[t] = bdv;
    __syncthreads();
    for (int off = 128; off > 0; off >>= 1) {
        if (t < off) s[t] += s[t + off];
        __syncthreads();
    }
    if (t == 0) partials[blockIdx.x] = s[0];
}

// ---------------------------------------------------------------------------
// Gather: out0[b, c, hw] = cb[code][c]  (f32)
// ---------------------------------------------------------------------------
__global__ __launch_bounds__(256) void vq_gather_kernel(
    const float* __restrict__ cb, const int* __restrict__ idx,
    float* __restrict__ out0)
{
    const int blk = blockIdx.x;          // 1024
    const int b   = blk >> 4;
    const int hw0 = (blk & 15) << 6;
    const int lane = threadIdx.x & 63;
    const int w    = threadIdx.x >> 6;

    __shared__ int sidx[64];
    if (threadIdx.x < 64) sidx[threadIdx.x] = idx[(blk << 6) + threadIdx.x];
    __syncthreads();

    const int code = sidx[lane];
    const float4* crow4 = reinterpret_cast<const float4*>(cb + ((size_t)code << 8) + (w << 6));
    float* ob = out0 + ((size_t)b << 18) + ((size_t)(w * 64) << 10) + hw0 + lane;
    #pragma unroll 4
    for (int j4 = 0; j4 < 16; ++j4) {
        float4 v = crow4[j4];
        ob[(size_t)(j4 * 4 + 0) << 10] = v.x;
        ob[(size_t)(j4 * 4 + 1) << 10] = v.y;
        ob[(size_t)(j4 * 4 + 2) << 10] = v.z;
        ob[(size_t)(j4 * 4 + 3) << 10] = v.w;
    }
}

// ---------------------------------------------------------------------------
// Finalize: loss = 1.25 * sum(partials[0..255]) / 2^24
// ---------------------------------------------------------------------------
__global__ __launch_bounds__(256) void vq_finalize_kernel(
    const float* __restrict__ partials, float* __restrict__ out2)
{
    __shared__ float s[256];
    const int t = threadIdx.x;
    s[t] = partials[t];
    __syncthreads();
    for (int off = 128; off > 0; off >>= 1) {
        if (t < off) s[t] += s[t + off];
        __syncthreads();
    }
    if (t == 0)
        out2[0] = 1.25f * (s[0] * (1.0f / 16777216.0f));
}

// ---------------------------------------------------------------------------
extern "C" void kernel_launch(void* const* d_in, const int* in_sizes, int n_in,
                              void* d_out, int out_size, void* d_ws, size_t ws_size,
                              hipStream_t stream)
{
    const float* z  = (const float*)d_in[0];
    const float* cb = (const float*)d_in[1];

    float* out0 = (float*)d_out;                  // z_q_st  (16777216 f32)
    float* out1 = out0 + OUT0_ELEMS;              // indices (65536 f32)
    float* out2 = out0 + OUT0_ELEMS + OUT1_ELEMS; // loss    (1 f32)

    // scratch carved from the out0 region (free until the gather runs):
    float* bd = out0;                        // 4*65536 f32 (1 MB)
    int*   bc = (int*)(out0 + 4 * N_POS);    // 4*65536 i32 (1 MB)
    float* zz = out0 + 8 * N_POS;            // 65536 f32  (256 KB)

    // ws: partials | cc | cbT | idx  (~790 KB)
    float* wsf      = (float*)d_ws;
    float* partials = wsf;                   // 256 f32
    float* ccv      = wsf + 256;             // 512 f32
    float* cbT      = wsf + 1024;            // 131072 f32
    int*   idx      = (int*)(wsf + 1024 + C_DIM * K_CODES);  // 65536 i32

    hipLaunchKernelGGL(vq_transpose_kernel, dim3(512),  dim3(256), 0, stream, cb, cbT);
    hipLaunchKernelGGL(vq_cc_kernel,        dim3(2),    dim3(256), 0, stream, cbT, ccv);
    hipLaunchKernelGGL(vq_zz_kernel,        dim3(256),  dim3(256), 0, stream, z, zz);
    hipLaunchKernelGGL(vq_main_kernel,      dim3(2048), dim3(256), 0, stream,
                       z, cbT, ccv, zz, bd, bc);
    hipLaunchKernelGGL(vq_combine_kernel,   dim3(256),  dim3(256), 0, stream,
                       bd, bc, idx, out1, partials);
    hipLaunchKernelGGL(vq_gather_kernel,    dim3(1024), dim3(256), 0, stream, cb, idx, out0);
    hipLaunchKernelGGL(vq_finalize_kernel,  dim3(1),    dim3(256), 0, stream, partials, out2);
}